// Round 1
// baseline (15348.213 us; speedup 1.0000x reference)
//
#include <hip/hip_runtime.h>
#include <stdint.h>

typedef short bf16x8 __attribute__((ext_vector_type(8)));
typedef float f32x4 __attribute__((ext_vector_type(4)));
typedef unsigned int u32;
typedef unsigned short u16;

__device__ __forceinline__ float b2f(u16 h) {
  union { float f; u32 u; } x; x.u = ((u32)h) << 16; return x.f;
}
__device__ __forceinline__ u16 f2b(float f) {
  union { float f; u32 u; } x; x.f = f;
  u32 u = x.u;
  return (u16)((u + 0x7fffu + ((u >> 16) & 1u)) >> 16);
}
__device__ __forceinline__ float hsig(float z) {
  return fminf(fmaxf(__builtin_fmaf(0.2f, z, 0.5f), 0.f), 1.f);
}
__device__ __forceinline__ float tanh_fast(float x) {
  float xa = fminf(fmaxf(x, -15.f), 15.f);
  float e = __expf(2.f * xa);
  return (e - 1.f) / (e + 1.f);
}

// ---------------- fp32 -> bf16 convert (vectorized) ----------------
__global__ __launch_bounds__(256) void k_cvt(const float* __restrict__ in,
                                             u16* __restrict__ out, int n4) {
  int i = blockIdx.x * 256 + threadIdx.x;
  if (i >= n4) return;
  const float4 v = reinterpret_cast<const float4*>(in)[i];
  ushort4 o;
  o.x = f2b(v.x); o.y = f2b(v.y); o.z = f2b(v.z); o.w = f2b(v.w);
  reinterpret_cast<ushort4*>(out)[i] = o;
}

// ------------- fp32 [1024][4096] -> bf16 transposed [4096][1024] -------------
__global__ __launch_bounds__(256) void k_trcvt(const float* __restrict__ in,
                                               u16* __restrict__ out) {
  __shared__ float t[32][33];
  const int x = threadIdx.x & 31;
  const int y0 = threadIdx.x >> 5; // 0..7
  const int c0 = blockIdx.x * 32;  // input col base (0..4095)
  const int r0 = blockIdx.y * 32;  // input row base (0..1023)
#pragma unroll
  for (int yy = 0; yy < 32; yy += 8)
    t[y0 + yy][x] = in[(size_t)(r0 + y0 + yy) * 4096 + c0 + x];
  __syncthreads();
#pragma unroll
  for (int yy = 0; yy < 32; yy += 8)
    out[(size_t)(c0 + y0 + yy) * 1024 + r0 + x] = f2b(t[x][y0 + yy]);
}

// ---------------- GEMM: xw = x(bf16 MxK) @ W (via W^T bf16 NxK) ----------------
// M=32768, N=4096, K=1024. Tile 128x128, BK=32, 4 waves (each 64x64).
// Output row remapped: row m=b*1024+s  ->  orow = s*32+b  (so scan reads [t][b][:]).
__global__ __launch_bounds__(256) void k_gemm(const u16* __restrict__ A,
                                              const u16* __restrict__ BT,
                                              u16* __restrict__ C) {
  __shared__ u16 Al[128 * 32];
  __shared__ u16 Bl[128 * 32];
  const int tid = threadIdx.x;
  const int lane = tid & 63;
  const int w = tid >> 6;
  const int mbase = blockIdx.y * 128;
  const int nbase = blockIdx.x * 128;
  const int wr = (w >> 1) * 64, wc = (w & 1) * 64;
  const int g = lane >> 4, rr = lane & 15;
  f32x4 acc[4][4] = {};

  for (int kt = 0; kt < 32; ++kt) {
    // ---- stage A,B tiles (reg->LDS, XOR swizzle: slot ^= (row>>1)&3) ----
#pragma unroll
    for (int c = 0; c < 2; ++c) {
      int T = c * 256 + tid;     // 0..511
      int r = T >> 2;            // 0..127
      int ks = T & 3;            // 16B slot
      int slot = ks ^ ((r >> 1) & 3);
      const u16* ga = A + (size_t)(mbase + r) * 1024 + kt * 32 + ks * 8;
      *reinterpret_cast<bf16x8*>(reinterpret_cast<char*>(Al) + r * 64 + slot * 16) =
          *reinterpret_cast<const bf16x8*>(ga);
      const u16* gb = BT + (size_t)(nbase + r) * 1024 + kt * 32 + ks * 8;
      *reinterpret_cast<bf16x8*>(reinterpret_cast<char*>(Bl) + r * 64 + slot * 16) =
          *reinterpret_cast<const bf16x8*>(gb);
    }
    __syncthreads();
    // ---- fragments + MFMA ----
    bf16x8 af[4], bfr[4];
#pragma unroll
    for (int mi = 0; mi < 4; ++mi) {
      int row = wr + mi * 16 + rr;
      int slot = g ^ ((row >> 1) & 3);
      af[mi] = *reinterpret_cast<const bf16x8*>(
          reinterpret_cast<const char*>(Al) + row * 64 + slot * 16);
      int coln = wc + mi * 16 + rr;
      int slotb = g ^ ((coln >> 1) & 3);
      bfr[mi] = *reinterpret_cast<const bf16x8*>(
          reinterpret_cast<const char*>(Bl) + coln * 64 + slotb * 16);
    }
#pragma unroll
    for (int mi = 0; mi < 4; ++mi)
#pragma unroll
      for (int ni = 0; ni < 4; ++ni)
        acc[mi][ni] = __builtin_amdgcn_mfma_f32_16x16x32_bf16(af[mi], bfr[ni],
                                                              acc[mi][ni], 0, 0, 0);
    __syncthreads();
  }
  // ---- epilogue: C layout row=(l>>4)*4+i, col=l&15 ----
#pragma unroll
  for (int mi = 0; mi < 4; ++mi)
#pragma unroll
    for (int ni = 0; ni < 4; ++ni)
#pragma unroll
      for (int i = 0; i < 4; ++i) {
        int mrow = mbase + wr + mi * 16 + g * 4 + i;
        int col = nbase + wc + ni * 16 + rr;
        int orow = (mrow & 1023) * 32 + (mrow >> 10);
        C[(size_t)orow * 4096 + col] = f2b(acc[mi][ni][i]);
      }
}

// ---------------- flag zeroing ----------------
__global__ void k_zflags(u32* f) { f[threadIdx.x] = 0; }

// ---------------- grid barrier: per-block flag, no atomic contention ----------------
__device__ __forceinline__ void gbar(u32* flags, int bid, u32 epoch, int tid) {
  __syncthreads();
  if (tid < 64) {
    __threadfence();  // release: publish this block's stores (h, out)
    if (tid == 0)
      __hip_atomic_store(&flags[bid], epoch, __ATOMIC_RELAXED,
                         __HIP_MEMORY_SCOPE_AGENT);
    while (__hip_atomic_load(&flags[tid], __ATOMIC_RELAXED,
                             __HIP_MEMORY_SCOPE_AGENT) < epoch) {}
    __threadfence();  // acquire: invalidate stale L1/L2
  }
  __syncthreads();
}

// ---------------- persistent LSTM scan ----------------
// 64 blocks x 256 threads. Block owns units [u0,u0+16). R^T slice (4 gates x 16
// units x 1024 K, bf16, XOR-swizzled) lives in LDS (128 KB). c in LDS (fp32).
// Per step: wave g computes z_g = h @ R_g via MFMA (2 row-tiles of 16 batches),
// dumps to LDS; all threads do gate math; one grid barrier per step.
__global__ __launch_bounds__(256, 1) void k_scan(const u16* __restrict__ rT,
                                                 const u16* __restrict__ xw,
                                                 u16* __restrict__ hbuf,
                                                 float* __restrict__ out,
                                                 u32* __restrict__ flags) {
  __shared__ u16 Rl[65536];         // 128 KB: [gate][unit][1024 k] swizzled
  __shared__ float zl[4][32][16];   // 8 KB
  __shared__ float cl[512];         // 2 KB: c[b*16+uu]
  const int tid = threadIdx.x, lane = tid & 63, w = tid >> 6;
  const int bid = blockIdx.x;
  const int u0 = bid * 16;
  const int g = w;                  // wave = gate
  const int kg = lane >> 4, rr = lane & 15;

  // ---- preload R^T slice into swizzled LDS (u32 words) ----
  for (int i = tid; i < 32768; i += 256) {
    int gg = i >> 13, j = (i >> 9) & 15, kp = i & 511;
    u32 v = *reinterpret_cast<const u32*>(rT + (size_t)(gg * 1024 + u0 + j) * 1024 +
                                          kp * 2);
    int byte = (gg * 16 + j) * 2048 + ((kp * 4) ^ ((j & 7) << 4));
    *reinterpret_cast<u32*>(reinterpret_cast<char*>(Rl) + byte) = v;
  }
  // ---- zero c and our slice of h0 ----
  for (int i = tid; i < 512; i += 256) cl[i] = 0.f;
  for (int i = tid; i < 512; i += 256) {
    int b = i >> 4, uu = i & 15;
    hbuf[(size_t)b * 1024 + u0 + uu] = 0;
  }
  gbar(flags, bid, 1u, tid);

  for (int t = 0; t < 1024; ++t) {
    const u16* h = hbuf + (size_t)(t & 1) * 32768;
    f32x4 acc0 = {0.f, 0.f, 0.f, 0.f}, acc1 = {0.f, 0.f, 0.f, 0.f};
#pragma unroll 4
    for (int kt = 0; kt < 32; ++kt) {
      int kb = kt * 32 + kg * 8;
      bf16x8 a0 = *reinterpret_cast<const bf16x8*>(h + (size_t)rr * 1024 + kb);
      bf16x8 a1 = *reinterpret_cast<const bf16x8*>(h + (size_t)(16 + rr) * 1024 + kb);
      int byte = (g * 16 + rr) * 2048 + ((kb * 2) ^ ((rr & 7) << 4));
      bf16x8 br = *reinterpret_cast<const bf16x8*>(
          reinterpret_cast<const char*>(Rl) + byte);
      acc0 = __builtin_amdgcn_mfma_f32_16x16x32_bf16(a0, br, acc0, 0, 0, 0);
      acc1 = __builtin_amdgcn_mfma_f32_16x16x32_bf16(a1, br, acc1, 0, 0, 0);
    }
#pragma unroll
    for (int i = 0; i < 4; ++i) {
      zl[g][kg * 4 + i][rr] = acc0[i];
      zl[g][16 + kg * 4 + i][rr] = acc1[i];
    }
    __syncthreads();
    // ---- gate math: thread -> 2 consecutive units of one batch ----
    {
      const int idx0 = tid << 1;
      const int b = idx0 >> 4;
      const int uu = idx0 & 15;
      const u16* xr = xw + (size_t)(t * 32 + b) * 4096 + u0 + uu;
      float zi0 = zl[0][b][uu] + b2f(xr[0]);
      float zi1 = zl[0][b][uu + 1] + b2f(xr[1]);
      float zf0 = zl[1][b][uu] + b2f(xr[1024]);
      float zf1 = zl[1][b][uu + 1] + b2f(xr[1025]);
      float zc0 = zl[2][b][uu] + b2f(xr[2048]);
      float zc1 = zl[2][b][uu + 1] + b2f(xr[2049]);
      float zo0 = zl[3][b][uu] + b2f(xr[3072]);
      float zo1 = zl[3][b][uu + 1] + b2f(xr[3073]);
      float it0 = hsig(zi0), it1 = hsig(zi1);
      float ft0 = hsig(zf0), ft1 = hsig(zf1);
      float cb0 = tanh_fast(zc0), cb1 = tanh_fast(zc1);
      float ot0 = hsig(zo0), ot1 = hsig(zo1);
      float c0 = ft0 * cl[idx0] + it0 * cb0;
      float c1 = ft1 * cl[idx0 + 1] + it1 * cb1;
      c0 = tanh_fast(c0);  // NOTE: reference carries tanh'd c
      c1 = tanh_fast(c1);
      cl[idx0] = c0;
      cl[idx0 + 1] = c1;
      float h0 = ot0 * c0, h1 = ot1 * c1;
      *reinterpret_cast<float2*>(out + (size_t)b * 1048576 + (size_t)t * 1024 +
                                 u0 + uu) = make_float2(h0, h1);
      u32 hw = (u32)f2b(h0) | ((u32)f2b(h1) << 16);
      *reinterpret_cast<u32*>(hbuf + (size_t)((t + 1) & 1) * 32768 + b * 1024 +
                              u0 + uu) = hw;
    }
    gbar(flags, bid, (u32)(t + 2), tid);
  }
}

extern "C" void kernel_launch(void* const* d_in, const int* in_sizes, int n_in,
                              void* d_out, int out_size, void* d_ws, size_t ws_size,
                              hipStream_t stream) {
  (void)in_sizes; (void)n_in; (void)out_size; (void)ws_size;
  const float* x = (const float*)d_in[0];      // [32][1024][1024]
  const float* kern = (const float*)d_in[1];   // [1024][4096]
  const float* rker = (const float*)d_in[2];   // [1024][4096]
  float* out = (float*)d_out;                  // [32][1024][1024]
  char* ws = (char*)d_ws;

  // Workspace layout (total ~337 MB):
  u16* xbf = (u16*)ws;                                   // 67,108,864 B
  u16* kT = (u16*)(ws + 67108864);                       //  8,388,608 B
  u16* rT = (u16*)(ws + 67108864 + 8388608);             //  8,388,608 B
  u16* xw = (u16*)(ws + 83886080);                       // 268,435,456 B
  u16* hbuf = (u16*)(ws + 83886080 + 268435456);         //    131,072 B (2 bufs)
  u32* flags = (u32*)(ws + 352321536 + 131072);          //        256 B

  k_cvt<<<32768, 256, 0, stream>>>(x, xbf, 8388608);
  k_trcvt<<<dim3(128, 32), 256, 0, stream>>>(kern, kT);
  k_trcvt<<<dim3(128, 32), 256, 0, stream>>>(rker, rT);
  k_gemm<<<dim3(32, 256), 256, 0, stream>>>(xbf, kT, xw);
  k_zflags<<<1, 64, 0, stream>>>(flags);
  k_scan<<<64, 256, 0, stream>>>(rT, xw, hbuf, out, flags);
}

// Round 2
// 6561.430 us; speedup vs baseline: 2.3392x; 2.3392x over previous
//
#include <hip/hip_runtime.h>
#include <stdint.h>

typedef short bf16x8 __attribute__((ext_vector_type(8)));
typedef float f32x4 __attribute__((ext_vector_type(4)));
typedef unsigned int u32;
typedef unsigned short u16;
typedef unsigned long long u64;

__device__ __forceinline__ float b2f(u16 h) {
  union { float f; u32 u; } x; x.u = ((u32)h) << 16; return x.f;
}
__device__ __forceinline__ u16 f2b(float f) {
  union { float f; u32 u; } x; x.f = f;
  u32 u = x.u;
  return (u16)((u + 0x7fffu + ((u >> 16) & 1u)) >> 16);
}
__device__ __forceinline__ float hsig(float z) {
  return fminf(fmaxf(__builtin_fmaf(0.2f, z, 0.5f), 0.f), 1.f);
}
__device__ __forceinline__ float tanh_fast(float x) {
  float xa = fminf(fmaxf(x, -15.f), 15.f);
  float e = __expf(2.f * xa);
  return (e - 1.f) / (e + 1.f);
}

// ---------------- fp32 -> bf16 convert (vectorized) ----------------
__global__ __launch_bounds__(256) void k_cvt(const float* __restrict__ in,
                                             u16* __restrict__ out, int n4) {
  int i = blockIdx.x * 256 + threadIdx.x;
  if (i >= n4) return;
  const float4 v = reinterpret_cast<const float4*>(in)[i];
  ushort4 o;
  o.x = f2b(v.x); o.y = f2b(v.y); o.z = f2b(v.z); o.w = f2b(v.w);
  reinterpret_cast<ushort4*>(out)[i] = o;
}

// ------------- fp32 [1024][4096] -> bf16 transposed [4096][1024] -------------
__global__ __launch_bounds__(256) void k_trcvt(const float* __restrict__ in,
                                               u16* __restrict__ out) {
  __shared__ float t[32][33];
  const int x = threadIdx.x & 31;
  const int y0 = threadIdx.x >> 5;
  const int c0 = blockIdx.x * 32;
  const int r0 = blockIdx.y * 32;
#pragma unroll
  for (int yy = 0; yy < 32; yy += 8)
    t[y0 + yy][x] = in[(size_t)(r0 + y0 + yy) * 4096 + c0 + x];
  __syncthreads();
#pragma unroll
  for (int yy = 0; yy < 32; yy += 8)
    out[(size_t)(c0 + y0 + yy) * 1024 + r0 + x] = f2b(t[x][y0 + yy]);
}

// ---------------- GEMM: xw = x(bf16 MxK) @ W (via W^T bf16 NxK) ----------------
__global__ __launch_bounds__(256) void k_gemm(const u16* __restrict__ A,
                                              const u16* __restrict__ BT,
                                              u16* __restrict__ C) {
  __shared__ u16 Al[128 * 32];
  __shared__ u16 Bl[128 * 32];
  const int tid = threadIdx.x;
  const int lane = tid & 63;
  const int w = tid >> 6;
  const int mbase = blockIdx.y * 128;
  const int nbase = blockIdx.x * 128;
  const int wr = (w >> 1) * 64, wc = (w & 1) * 64;
  const int g = lane >> 4, rr = lane & 15;
  f32x4 acc[4][4] = {};

  for (int kt = 0; kt < 32; ++kt) {
#pragma unroll
    for (int c = 0; c < 2; ++c) {
      int T = c * 256 + tid;
      int r = T >> 2;
      int ks = T & 3;
      int slot = ks ^ ((r >> 1) & 3);
      const u16* ga = A + (size_t)(mbase + r) * 1024 + kt * 32 + ks * 8;
      *reinterpret_cast<bf16x8*>(reinterpret_cast<char*>(Al) + r * 64 + slot * 16) =
          *reinterpret_cast<const bf16x8*>(ga);
      const u16* gb = BT + (size_t)(nbase + r) * 1024 + kt * 32 + ks * 8;
      *reinterpret_cast<bf16x8*>(reinterpret_cast<char*>(Bl) + r * 64 + slot * 16) =
          *reinterpret_cast<const bf16x8*>(gb);
    }
    __syncthreads();
    bf16x8 af[4], bfr[4];
#pragma unroll
    for (int mi = 0; mi < 4; ++mi) {
      int row = wr + mi * 16 + rr;
      int slot = g ^ ((row >> 1) & 3);
      af[mi] = *reinterpret_cast<const bf16x8*>(
          reinterpret_cast<const char*>(Al) + row * 64 + slot * 16);
      int coln = wc + mi * 16 + rr;
      int slotb = g ^ ((coln >> 1) & 3);
      bfr[mi] = *reinterpret_cast<const bf16x8*>(
          reinterpret_cast<const char*>(Bl) + coln * 64 + slotb * 16);
    }
#pragma unroll
    for (int mi = 0; mi < 4; ++mi)
#pragma unroll
      for (int ni = 0; ni < 4; ++ni)
        acc[mi][ni] = __builtin_amdgcn_mfma_f32_16x16x32_bf16(af[mi], bfr[ni],
                                                              acc[mi][ni], 0, 0, 0);
    __syncthreads();
  }
#pragma unroll
  for (int mi = 0; mi < 4; ++mi)
#pragma unroll
    for (int ni = 0; ni < 4; ++ni)
#pragma unroll
      for (int i = 0; i < 4; ++i) {
        int mrow = mbase + wr + mi * 16 + g * 4 + i;
        int col = nbase + wc + ni * 16 + rr;
        int orow = (mrow & 1023) * 32 + (mrow >> 10);
        C[(size_t)orow * 4096 + col] = f2b(acc[mi][ni][i]);
      }
}

// ---------------- zero h0 + flags ----------------
__global__ __launch_bounds__(256) void k_zinit(u32* __restrict__ hb0,
                                               u32* __restrict__ flags) {
  int i = blockIdx.x * 256 + threadIdx.x;  // grid = 64*256 = 16384 exactly
  hb0[i] = 0;
  if (i < 64) flags[i] = 0;
}

// coherent 16B load from L3 (bypasses L2 via agent-scope atomics)
__device__ __forceinline__ bf16x8 ld16_agent(const u16* p) {
  union { bf16x8 v; u64 q[2]; } r;
  r.q[0] = __hip_atomic_load((const u64*)p, __ATOMIC_RELAXED,
                             __HIP_MEMORY_SCOPE_AGENT);
  r.q[1] = __hip_atomic_load((const u64*)(p + 4), __ATOMIC_RELAXED,
                             __HIP_MEMORY_SCOPE_AGENT);
  return r.v;
}

// ---------------- persistent LSTM scan ----------------
// 64 blocks x 512 threads (8 waves). wave = (gate g, K-half kh).
// R fragments live in VGPRs (16 x bf16x8 per lane). h staged once per block
// per step into XOR-swizzled LDS. c carried in registers. All cross-block
// traffic via agent-scope atomics (L2-bypass, no cache invalidation).
__global__ __launch_bounds__(512, 2) void k_scan(const u16* __restrict__ rT,
                                                 const u16* __restrict__ xw,
                                                 u16* __restrict__ hbuf,
                                                 float* __restrict__ out,
                                                 u32* __restrict__ flags) {
  __shared__ char hl[65536];        // 64 KB: h[32][1024] bf16, swizzled
  __shared__ float zl[4][2][32][18]; // 18 KB padded partials

  const int tid = threadIdx.x;
  const int bid = blockIdx.x;
  const int u0 = bid * 16;
  const int wv = tid >> 6;          // 0..7
  const int g = wv >> 1;            // gate 0..3
  const int kh = wv & 1;            // K-half
  const int lane = tid & 63;
  const int kg = lane >> 4, rr = lane & 15;
  // staging mapping: row sr (0..31), 16 threads/row, 8 x 16B granules each
  const int sr = tid >> 4;
  const int sc = tid & 15;
  // gate-math mapping: 1 unit per thread
  const int b = tid >> 4;
  const int uu = tid & 15;

  // ---- R fragments -> registers (one gate x one K-half per wave) ----
  bf16x8 Rf[16];
  {
    const u16* rbase = rT + (size_t)(g * 1024 + u0 + rr) * 1024 + kh * 512 + kg * 8;
#pragma unroll
    for (int kt = 0; kt < 16; ++kt)
      Rf[kt] = *reinterpret_cast<const bf16x8*>(rbase + kt * 32);
  }

  float creg = 0.f;
  const int swz = (sr & 7) << 4;
  const int swr = (rr & 7) << 4;

  for (int t = 0; t < 1024; ++t) {
    // ---- xw prefetch for this step (consumed after MFMA; hidden) ----
    const u16* xr = xw + (size_t)(t * 32 + b) * 4096 + u0 + uu;
    u16 xg0 = xr[0], xg1 = xr[1024], xg2 = xr[2048], xg3 = xr[3072];

    // ---- stage h[t] from L3 into swizzled LDS (coherent loads) ----
    {
      const u16* hsrc = hbuf + (size_t)(t & 1) * 32768 + sr * 1024 + sc * 8;
      u64 q0[8], q1[8];
#pragma unroll
      for (int q = 0; q < 8; ++q) {
        q0[q] = __hip_atomic_load((const u64*)(hsrc + q * 128), __ATOMIC_RELAXED,
                                  __HIP_MEMORY_SCOPE_AGENT);
        q1[q] = __hip_atomic_load((const u64*)(hsrc + q * 128 + 4), __ATOMIC_RELAXED,
                                  __HIP_MEMORY_SCOPE_AGENT);
      }
#pragma unroll
      for (int q = 0; q < 8; ++q) {
        union { bf16x8 v; u64 w[2]; } u;
        u.w[0] = q0[q]; u.w[1] = q1[q];
        int byte = sr * 2048 + (((sc + 16 * q) * 16) ^ swz);
        *reinterpret_cast<bf16x8*>(hl + byte) = u.v;
      }
    }
    __syncthreads();  // hl ready

    // ---- z = h @ R (this wave: gate g, K-half kh), 4 indep chains ----
    f32x4 aA = {0.f, 0.f, 0.f, 0.f}, aB = {0.f, 0.f, 0.f, 0.f};
    f32x4 bA = {0.f, 0.f, 0.f, 0.f}, bB = {0.f, 0.f, 0.f, 0.f};
#pragma unroll
    for (int kt = 0; kt < 16; ++kt) {
      int cb = kh * 1024 + kt * 64 + kg * 16;
      bf16x8 a0 = *reinterpret_cast<const bf16x8*>(hl + rr * 2048 + (cb ^ swr));
      bf16x8 a1 = *reinterpret_cast<const bf16x8*>(hl + (16 + rr) * 2048 + (cb ^ swr));
      if (kt & 1) {
        aB = __builtin_amdgcn_mfma_f32_16x16x32_bf16(a0, Rf[kt], aB, 0, 0, 0);
        bB = __builtin_amdgcn_mfma_f32_16x16x32_bf16(a1, Rf[kt], bB, 0, 0, 0);
      } else {
        aA = __builtin_amdgcn_mfma_f32_16x16x32_bf16(a0, Rf[kt], aA, 0, 0, 0);
        bA = __builtin_amdgcn_mfma_f32_16x16x32_bf16(a1, Rf[kt], bA, 0, 0, 0);
      }
    }
    f32x4 z0 = aA + aB, z1 = bA + bB;
#pragma unroll
    for (int i = 0; i < 4; ++i) {
      zl[g][kh][kg * 4 + i][rr] = z0[i];
      zl[g][kh][16 + kg * 4 + i][rr] = z1[i];
    }
    __syncthreads();  // zl ready (also fences hl WAR for next step)

    // ---- gate math: 1 unit per thread, c in register ----
    {
      float zi = zl[0][0][b][uu] + zl[0][1][b][uu] + b2f(xg0);
      float zf = zl[1][0][b][uu] + zl[1][1][b][uu] + b2f(xg1);
      float zc = zl[2][0][b][uu] + zl[2][1][b][uu] + b2f(xg2);
      float zo = zl[3][0][b][uu] + zl[3][1][b][uu] + b2f(xg3);
      float it = hsig(zi), ft = hsig(zf);
      float cb2 = tanh_fast(zc), ot = hsig(zo);
      creg = tanh_fast(ft * creg + it * cb2);  // reference carries tanh'd c
      float hv = ot * creg;
      out[(size_t)b * 1048576 + (size_t)t * 1024 + u0 + uu] = hv;
      __hip_atomic_store(hbuf + (size_t)((t + 1) & 1) * 32768 + b * 1024 + u0 + uu,
                         f2b(hv), __ATOMIC_RELAXED, __HIP_MEMORY_SCOPE_AGENT);
    }

    // ---- grid barrier: drain -> signal -> poll (no L2 invalidation) ----
    if (t < 1023) {
      asm volatile("s_waitcnt vmcnt(0)" ::: "memory");
      __syncthreads();  // all waves' h stores drained to L3
      if (tid == 0)
        __hip_atomic_store(&flags[bid], (u32)(t + 1), __ATOMIC_RELAXED,
                           __HIP_MEMORY_SCOPE_AGENT);
      if (tid < 64)
        while (__hip_atomic_load(&flags[tid], __ATOMIC_RELAXED,
                                 __HIP_MEMORY_SCOPE_AGENT) < (u32)(t + 1)) {}
      __syncthreads();
    }
  }
}

extern "C" void kernel_launch(void* const* d_in, const int* in_sizes, int n_in,
                              void* d_out, int out_size, void* d_ws, size_t ws_size,
                              hipStream_t stream) {
  (void)in_sizes; (void)n_in; (void)out_size; (void)ws_size;
  const float* x = (const float*)d_in[0];
  const float* kern = (const float*)d_in[1];
  const float* rker = (const float*)d_in[2];
  float* out = (float*)d_out;
  char* ws = (char*)d_ws;

  u16* xbf = (u16*)ws;                                   // 67,108,864 B
  u16* kT = (u16*)(ws + 67108864);                       //  8,388,608 B
  u16* rT = (u16*)(ws + 67108864 + 8388608);             //  8,388,608 B
  u16* xw = (u16*)(ws + 83886080);                       // 268,435,456 B
  u16* hbuf = (u16*)(ws + 83886080 + 268435456);         //    131,072 B
  u32* flags = (u32*)(ws + 352321536 + 131072);          //        256 B

  k_cvt<<<32768, 256, 0, stream>>>(x, xbf, 8388608);
  k_trcvt<<<dim3(128, 32), 256, 0, stream>>>(kern, kT);
  k_trcvt<<<dim3(128, 32), 256, 0, stream>>>(rker, rT);
  k_gemm<<<dim3(32, 256), 256, 0, stream>>>(xbf, kT, xw);
  k_zinit<<<64, 256, 0, stream>>>((u32*)hbuf, flags);
  k_scan<<<64, 512, 0, stream>>>(rT, xw, hbuf, out, flags);
}

// Round 3
// 5352.489 us; speedup vs baseline: 2.8675x; 1.2259x over previous
//
#include <hip/hip_runtime.h>
#include <stdint.h>

typedef short bf16x8 __attribute__((ext_vector_type(8)));
typedef float f32x4 __attribute__((ext_vector_type(4)));
typedef unsigned int u32;
typedef unsigned short u16;
typedef unsigned long long u64;
typedef u32 u32x4 __attribute__((ext_vector_type(4)));

__device__ __forceinline__ float b2f(u16 h) {
  union { float f; u32 u; } x; x.u = ((u32)h) << 16; return x.f;
}
__device__ __forceinline__ u16 f2b(float f) {
  union { float f; u32 u; } x; x.f = f;
  u32 u = x.u;
  return (u16)((u + 0x7fffu + ((u >> 16) & 1u)) >> 16);
}
__device__ __forceinline__ float hsig(float z) {
  return fminf(fmaxf(__builtin_fmaf(0.2f, z, 0.5f), 0.f), 1.f);
}
__device__ __forceinline__ float tanh_fast(float x) {
  float xa = fminf(fmaxf(x, -15.f), 15.f);
  float e = __expf(2.f * xa);
  return (e - 1.f) / (e + 1.f);
}

// ---------------- fp32 -> bf16 convert (vectorized) ----------------
__global__ __launch_bounds__(256) void k_cvt(const float* __restrict__ in,
                                             u16* __restrict__ out, int n4) {
  int i = blockIdx.x * 256 + threadIdx.x;
  if (i >= n4) return;
  const float4 v = reinterpret_cast<const float4*>(in)[i];
  ushort4 o;
  o.x = f2b(v.x); o.y = f2b(v.y); o.z = f2b(v.z); o.w = f2b(v.w);
  reinterpret_cast<ushort4*>(out)[i] = o;
}

// ------------- fp32 [1024][4096] -> bf16 transposed [4096][1024] -------------
__global__ __launch_bounds__(256) void k_trcvt(const float* __restrict__ in,
                                               u16* __restrict__ out) {
  __shared__ float t[32][33];
  const int x = threadIdx.x & 31;
  const int y0 = threadIdx.x >> 5;
  const int c0 = blockIdx.x * 32;
  const int r0 = blockIdx.y * 32;
#pragma unroll
  for (int yy = 0; yy < 32; yy += 8)
    t[y0 + yy][x] = in[(size_t)(r0 + y0 + yy) * 4096 + c0 + x];
  __syncthreads();
#pragma unroll
  for (int yy = 0; yy < 32; yy += 8)
    out[(size_t)(c0 + y0 + yy) * 1024 + r0 + x] = f2b(t[x][y0 + yy]);
}

// ---------------- GEMM: xw = x(bf16 MxK) @ W (via W^T bf16 NxK) ----------------
__global__ __launch_bounds__(256) void k_gemm(const u16* __restrict__ A,
                                              const u16* __restrict__ BT,
                                              u16* __restrict__ C) {
  __shared__ u16 Al[128 * 32];
  __shared__ u16 Bl[128 * 32];
  const int tid = threadIdx.x;
  const int lane = tid & 63;
  const int w = tid >> 6;
  const int mbase = blockIdx.y * 128;
  const int nbase = blockIdx.x * 128;
  const int wr = (w >> 1) * 64, wc = (w & 1) * 64;
  const int g = lane >> 4, rr = lane & 15;
  f32x4 acc[4][4] = {};

  for (int kt = 0; kt < 32; ++kt) {
#pragma unroll
    for (int c = 0; c < 2; ++c) {
      int T = c * 256 + tid;
      int r = T >> 2;
      int ks = T & 3;
      int slot = ks ^ ((r >> 1) & 3);
      const u16* ga = A + (size_t)(mbase + r) * 1024 + kt * 32 + ks * 8;
      *reinterpret_cast<bf16x8*>(reinterpret_cast<char*>(Al) + r * 64 + slot * 16) =
          *reinterpret_cast<const bf16x8*>(ga);
      const u16* gb = BT + (size_t)(nbase + r) * 1024 + kt * 32 + ks * 8;
      *reinterpret_cast<bf16x8*>(reinterpret_cast<char*>(Bl) + r * 64 + slot * 16) =
          *reinterpret_cast<const bf16x8*>(gb);
    }
    __syncthreads();
    bf16x8 af[4], bfr[4];
#pragma unroll
    for (int mi = 0; mi < 4; ++mi) {
      int row = wr + mi * 16 + rr;
      int slot = g ^ ((row >> 1) & 3);
      af[mi] = *reinterpret_cast<const bf16x8*>(
          reinterpret_cast<const char*>(Al) + row * 64 + slot * 16);
      int coln = wc + mi * 16 + rr;
      int slotb = g ^ ((coln >> 1) & 3);
      bfr[mi] = *reinterpret_cast<const bf16x8*>(
          reinterpret_cast<const char*>(Bl) + coln * 64 + slotb * 16);
    }
#pragma unroll
    for (int mi = 0; mi < 4; ++mi)
#pragma unroll
      for (int ni = 0; ni < 4; ++ni)
        acc[mi][ni] = __builtin_amdgcn_mfma_f32_16x16x32_bf16(af[mi], bfr[ni],
                                                              acc[mi][ni], 0, 0, 0);
    __syncthreads();
  }
#pragma unroll
  for (int mi = 0; mi < 4; ++mi)
#pragma unroll
    for (int ni = 0; ni < 4; ++ni)
#pragma unroll
      for (int i = 0; i < 4; ++i) {
        int mrow = mbase + wr + mi * 16 + g * 4 + i;
        int col = nbase + wc + ni * 16 + rr;
        int orow = (mrow & 1023) * 32 + (mrow >> 10);
        C[(size_t)orow * 4096 + col] = f2b(acc[mi][ni][i]);
      }
}

// ---------------- zero h0 + flags ----------------
__global__ __launch_bounds__(256) void k_zinit(u32* __restrict__ hb0,
                                               u32* __restrict__ flags) {
  int i = blockIdx.x * 256 + threadIdx.x;  // grid = 64*256 = 16384 exactly
  hb0[i] = 0;
  if (i < 64) flags[i] = 0;
}

// ---------------- persistent LSTM scan ----------------
// 32 blocks x 512 threads (8 waves). Block owns units [bid*32, +32).
// wave = (gate-pair j, K-half kh, unit-half uh): each A-fragment (from LDS)
// feeds 2 MFMAs (both gates of the pair) -> LDS A-traffic halved.
// R fragments in VGPRs (2 gates x 16 x bf16x8 = 128 VGPR/lane).
// h staged per step via coalesced sc1 (device-scope) dwordx4 loads -> swizzled
// LDS. c carried in registers. Grid barrier: drain -> flag -> poll (32 flags).
__global__ __launch_bounds__(512, 2) void k_scan(const u16* __restrict__ rT,
                                                 const u16* __restrict__ xw,
                                                 u16* __restrict__ hbuf,
                                                 float* __restrict__ out,
                                                 u32* __restrict__ flags) {
  __shared__ char hl[65536];          // h[32 batches][1024 K] bf16, swizzled
  __shared__ float zl[4][2][32][33];  // [gate][kh][batch][unit(pad)]

  const int tid = threadIdx.x;
  const int bid = blockIdx.x;
  const int u0 = bid * 32;
  const int w = tid >> 6;           // 0..7
  const int j = w >> 2;             // gate-pair 0..1 -> gates 2j, 2j+1
  const int kh = (w >> 1) & 1;      // K-half
  const int uh = w & 1;             // unit-half
  const int lane = tid & 63;
  const int kg = lane >> 4, rr = lane & 15;
  const int sr = tid >> 4;          // staging row / gate-math batch 0..31
  const int sc = tid & 15;
  const int uu = sc * 2;            // gate-math: 2 consecutive units

  // ---- R fragments -> registers: 2 gates x 16 kt ----
  bf16x8 Rf0[16], Rf1[16];
  {
    const u16* r0 = rT + (size_t)((2 * j) * 1024 + u0 + uh * 16 + rr) * 1024 +
                    kh * 512 + kg * 8;
    const u16* r1 = rT + (size_t)((2 * j + 1) * 1024 + u0 + uh * 16 + rr) * 1024 +
                    kh * 512 + kg * 8;
#pragma unroll
    for (int kt = 0; kt < 16; ++kt) {
      Rf0[kt] = *reinterpret_cast<const bf16x8*>(r0 + kt * 32);
      Rf1[kt] = *reinterpret_cast<const bf16x8*>(r1 + kt * 32);
    }
  }

  float c0 = 0.f, c1 = 0.f;
  const int swz = (sr & 7) << 4;
  const int swr = (rr & 7) << 4;

  for (int t = 0; t < 1024; ++t) {
    // ---- 8 coalesced device-scope stage loads (h[t], L2-bypass, L3-hit) ----
    u32x4 sv[8];
    const char* hsrc = reinterpret_cast<const char*>(hbuf + (size_t)(t & 1) * 32768) +
                       sr * 2048 + sc * 16;
#pragma unroll
    for (int q = 0; q < 8; ++q)
      asm volatile("global_load_dwordx4 %0, %1, off sc1"
                   : "=v"(sv[q]) : "v"(hsrc + q * 256));
    // ---- 4 xw loads, stay in flight across the MFMA phase ----
    u32 xq0, xq1, xq2, xq3;
    const u16* xb = xw + (size_t)(t * 32 + sr) * 4096 + u0 + uu;
    asm volatile("global_load_dword %0, %1, off" : "=v"(xq0) : "v"(xb));
    asm volatile("global_load_dword %0, %1, off" : "=v"(xq1) : "v"(xb + 1024));
    asm volatile("global_load_dword %0, %1, off" : "=v"(xq2) : "v"(xb + 2048));
    asm volatile("global_load_dword %0, %1, off" : "=v"(xq3) : "v"(xb + 3072));
    asm volatile("s_waitcnt vmcnt(4)" ::: "memory");  // stage loads done
    __builtin_amdgcn_sched_barrier(0);
#pragma unroll
    for (int q = 0; q < 8; ++q) {
      int byte = sr * 2048 + ((((sc + 16 * q) * 16)) ^ swz);
      *reinterpret_cast<u32x4*>(hl + byte) = sv[q];
    }
    __syncthreads();  // hl ready

    // ---- z = h @ R : 4 independent chains, shared A-fragments ----
    f32x4 a00 = {0.f,0.f,0.f,0.f}, a01 = {0.f,0.f,0.f,0.f};
    f32x4 a10 = {0.f,0.f,0.f,0.f}, a11 = {0.f,0.f,0.f,0.f};
#pragma unroll
    for (int kt = 0; kt < 16; ++kt) {
      int cb = kh * 1024 + kt * 64 + kg * 16;
      bf16x8 h0 = *reinterpret_cast<const bf16x8*>(hl + rr * 2048 + (cb ^ swr));
      bf16x8 h1 = *reinterpret_cast<const bf16x8*>(hl + (16 + rr) * 2048 + (cb ^ swr));
      a00 = __builtin_amdgcn_mfma_f32_16x16x32_bf16(h0, Rf0[kt], a00, 0, 0, 0);
      a01 = __builtin_amdgcn_mfma_f32_16x16x32_bf16(h1, Rf0[kt], a01, 0, 0, 0);
      a10 = __builtin_amdgcn_mfma_f32_16x16x32_bf16(h0, Rf1[kt], a10, 0, 0, 0);
      a11 = __builtin_amdgcn_mfma_f32_16x16x32_bf16(h1, Rf1[kt], a11, 0, 0, 0);
    }
#pragma unroll
    for (int i = 0; i < 4; ++i) {
      zl[2 * j][kh][kg * 4 + i][uh * 16 + rr] = a00[i];
      zl[2 * j][kh][16 + kg * 4 + i][uh * 16 + rr] = a01[i];
      zl[2 * j + 1][kh][kg * 4 + i][uh * 16 + rr] = a10[i];
      zl[2 * j + 1][kh][16 + kg * 4 + i][uh * 16 + rr] = a11[i];
    }
    __syncthreads();  // zl ready
    asm volatile("s_waitcnt vmcnt(0)" ::: "memory");  // xw values ready
    __builtin_amdgcn_sched_barrier(0);

    // ---- gate math: thread -> (batch sr, units uu,uu+1), c in registers ----
    {
      float zi0 = zl[0][0][sr][uu]     + zl[0][1][sr][uu]     + b2f((u16)xq0);
      float zi1 = zl[0][0][sr][uu + 1] + zl[0][1][sr][uu + 1] + b2f((u16)(xq0 >> 16));
      float zf0 = zl[1][0][sr][uu]     + zl[1][1][sr][uu]     + b2f((u16)xq1);
      float zf1 = zl[1][0][sr][uu + 1] + zl[1][1][sr][uu + 1] + b2f((u16)(xq1 >> 16));
      float zc0 = zl[2][0][sr][uu]     + zl[2][1][sr][uu]     + b2f((u16)xq2);
      float zc1 = zl[2][0][sr][uu + 1] + zl[2][1][sr][uu + 1] + b2f((u16)(xq2 >> 16));
      float zo0 = zl[3][0][sr][uu]     + zl[3][1][sr][uu]     + b2f((u16)xq3);
      float zo1 = zl[3][0][sr][uu + 1] + zl[3][1][sr][uu + 1] + b2f((u16)(xq3 >> 16));
      c0 = tanh_fast(hsig(zf0) * c0 + hsig(zi0) * tanh_fast(zc0));  // ref carries tanh'd c
      c1 = tanh_fast(hsig(zf1) * c1 + hsig(zi1) * tanh_fast(zc1));
      float h0 = hsig(zo0) * c0;
      float h1 = hsig(zo1) * c1;
      *reinterpret_cast<float2*>(out + (size_t)sr * 1048576 + (size_t)t * 1024 +
                                 u0 + uu) = make_float2(h0, h1);
      __hip_atomic_store(
          reinterpret_cast<u32*>(hbuf + (size_t)((t + 1) & 1) * 32768 + sr * 1024 +
                                 u0 + uu),
          (u32)f2b(h0) | ((u32)f2b(h1) << 16), __ATOMIC_RELAXED,
          __HIP_MEMORY_SCOPE_AGENT);
    }

    // ---- grid barrier: drain -> signal -> poll ----
    if (t < 1023) {
      asm volatile("s_waitcnt vmcnt(0)" ::: "memory");  // h (and out) drained
      __syncthreads();
      if (tid == 0)
        __hip_atomic_store(&flags[bid], (u32)(t + 1), __ATOMIC_RELAXED,
                           __HIP_MEMORY_SCOPE_AGENT);
      if (tid < 32)
        while (__hip_atomic_load(&flags[tid], __ATOMIC_RELAXED,
                                 __HIP_MEMORY_SCOPE_AGENT) < (u32)(t + 1)) {}
      __syncthreads();
    }
  }
}

extern "C" void kernel_launch(void* const* d_in, const int* in_sizes, int n_in,
                              void* d_out, int out_size, void* d_ws, size_t ws_size,
                              hipStream_t stream) {
  (void)in_sizes; (void)n_in; (void)out_size; (void)ws_size;
  const float* x = (const float*)d_in[0];
  const float* kern = (const float*)d_in[1];
  const float* rker = (const float*)d_in[2];
  float* out = (float*)d_out;
  char* ws = (char*)d_ws;

  u16* xbf = (u16*)ws;                                   // 67,108,864 B
  u16* kT = (u16*)(ws + 67108864);                       //  8,388,608 B
  u16* rT = (u16*)(ws + 67108864 + 8388608);             //  8,388,608 B
  u16* xw = (u16*)(ws + 83886080);                       // 268,435,456 B
  u16* hbuf = (u16*)(ws + 83886080 + 268435456);         //    131,072 B
  u32* flags = (u32*)(ws + 352321536 + 131072);          //        256 B

  k_cvt<<<32768, 256, 0, stream>>>(x, xbf, 8388608);
  k_trcvt<<<dim3(128, 32), 256, 0, stream>>>(kern, kT);
  k_trcvt<<<dim3(128, 32), 256, 0, stream>>>(rker, rT);
  k_gemm<<<dim3(32, 256), 256, 0, stream>>>(xbf, kT, xw);
  k_zinit<<<64, 256, 0, stream>>>((u32*)hbuf, flags);
  k_scan<<<32, 512, 0, stream>>>(rT, xw, hbuf, out, flags);
}